// Round 6
// baseline (129.517 us; speedup 1.0000x reference)
//
#include <hip/hip_runtime.h>
#include <stdint.h>

// ===========================================================================
// AnchorDataGenerator (Faster R-CNN anchor target layer), MI355X / gfx950
// Round 9: single worker kernel with CUSTOM cheap barriers.
//   memset(20.5KB ctrl) -> k_all (576 blocks, cooperative launch for the
//   co-residency guarantee only; sync is OUR tree-arrival + flag-spin, not
//   ockl grid.sync (70us/barrier) and not flat counters (28ns/RMW chain)).
// Phases inside k_all:
//   compute (analytic gmax + IoU + labels/adj + LDS hist; (lab,mant) stays
//   in REGISTERS - LABM buffer eliminated)
//   -> hist add -> tree arrival B -> completer: select -> SEL stores -> flag
//   -> all blocks spin flag (s_sleep), emit from regs (disjoint-writer
//      candidates) -> tree arrival D -> completer: O(C^2) fixup.
// Cross-XCD discipline (validated R7/R8): cross-block data via agent-scope
// atomics (performed at IF), vmcnt(0) drain before every arrival RMW, plain
// stores only for host-visible finals; fixup = sole writer of candidates.
// Fallback: proven Round-8 2-kernel path if cooperative launch rejected.
// ===========================================================================

#define NUM_A 9
#define HW 65536
#define N_ANCH 589824
#define NG 64
#define CAPK 128u
#define NBIN 2048
#define BIN_SHIFT 12
#define CAND_CAP 2048

#define LAB_BG 0u
#define LAB_FG 1u
#define LAB_IGN 2u

#define NBLK_MAIN 576

// ---- merged-kernel workspace layout (u32 units) ----
#define M_OFF_HF   0
#define M_OFF_HB   NBIN                      // 2048
#define M_OFF_CNTF (2*NBIN)                  // 4096
#define M_OFF_CNTB (M_OFF_CNTF + 1)          // 4097
#define M_ROOTB    (M_OFF_CNTF + 2)          // 4098
#define M_ROOTD    (M_OFF_CNTF + 3)          // 4099
#define M_FLAGC    (M_OFF_CNTF + 4)          // 4100
#define M_OFF_SEL  4104                      // ..4111 {bin,below,need,K}x2
#define M_SUBB     4112                      // 32 x stride16 = 512
#define M_SUBD     (M_SUBB + 32*16)          // 4624, 32 x stride16
#define M_CTRL     (M_SUBD + 32*16)          // 5136 words = 20.5 KB memset
#define M_CANDF    M_CTRL                    // 5136 (byte 20544, 8B aligned)
#define M_CANDB    (M_CANDF + 2*CAND_CAP)    // 9232

// ---- fallback (Round 8) layout ----
#define OFF_HF    0
#define OFF_HB    NBIN
#define OFF_CNTF  (2*NBIN)
#define OFF_CNTB  (OFF_CNTF + 1)
#define OFF_ROOT1 (OFF_CNTF + 2)
#define OFF_ROOT2 (OFF_CNTF + 3)
#define OFF_SEL   (OFF_CNTF + 4)
#define OFF_SUB1  4112
#define OFF_SUB2  (OFF_SUB1 + 32*16)
#define CTRL_WORDS (OFF_SUB2 + 64*16)        // 5648
#define OFF_CANDF CTRL_WORDS
#define OFF_CANDB (OFF_CANDF + 2*CAND_CAP)
#define OFF_LABM  (OFF_CANDB + 2*CAND_CAP)
#define NBLK_EMIT (N_ANCH / 256)
#define SUB1_N 32
#define SUB1_Q (NBLK_MAIN / SUB1_N)
#define SUB2_N 64
#define SUB2_Q (NBLK_EMIT / SUB2_N)

__constant__ float BA[NUM_A][4] = {
  { -84.f,  -40.f,  99.f,  55.f}, {-176.f,  -88.f, 191.f, 103.f},
  {-360.f, -184.f, 375.f, 199.f}, { -56.f,  -56.f,  71.f,  71.f},
  {-120.f, -120.f, 135.f, 135.f}, {-248.f, -248.f, 263.f, 263.f},
  { -36.f,  -80.f,  51.f,  95.f}, { -80.f, -168.f,  95.f, 183.f},
  {-168.f, -344.f, 183.f, 359.f}};

__host__ __device__ static inline void tf2x32(uint32_t k0, uint32_t k1,
                                              uint32_t x0, uint32_t x1,
                                              uint32_t* o0, uint32_t* o1) {
  const uint32_t ks2 = k0 ^ k1 ^ 0x1BD11BDAu;
#define TF_R(r) { x0 += x1; x1 = (x1 << (r)) | (x1 >> (32 - (r))); x1 ^= x0; }
  x0 += k0; x1 += k1;
  TF_R(13) TF_R(15) TF_R(26) TF_R(6)
  x0 += k1;  x1 += ks2 + 1u;
  TF_R(17) TF_R(29) TF_R(16) TF_R(24)
  x0 += ks2; x1 += k0 + 2u;
  TF_R(13) TF_R(15) TF_R(26) TF_R(6)
  x0 += k0;  x1 += k1 + 3u;
  TF_R(17) TF_R(29) TF_R(16) TF_R(24)
  x0 += k1;  x1 += ks2 + 4u;
  TF_R(13) TF_R(15) TF_R(26) TF_R(6)
  x0 += ks2; x1 += k0 + 5u;
#undef TF_R
  *o0 = x0; *o1 = x1;
}

__device__ static inline uint32_t mant_of(uint32_t k0, uint32_t k1, uint32_t n) {
  uint32_t o0, o1;
  tf2x32(k0, k1, 0u, n, &o0, &o1);
  return (o0 ^ o1) >> 9;
}

// Max of fl(iw) over valid integer shifts [lo,hi] for one axis (concave,
// unimodal; max at clamped floor/ceil of continuous argmax endpoints).
__device__ static inline float axis_best(float blo, float bhi, float glo,
                                         float ghi, int lo, int hi) {
  #pragma clang fp contract(off)
  float t1 = (ghi - bhi) * 0.0625f;
  float t2 = (glo - blo) * 0.0625f;
  float tmin = fminf(t1, t2), tmax = fmaxf(t1, t2);
  int c1 = (int)floorf(tmin), c2 = (int)ceilf(tmax);
  int cand0 = lo, cand1 = hi;
  int cand2 = min(max(c1,     lo), hi);
  int cand3 = min(max(c1 + 1, lo), hi);
  int cand4 = min(max(c2 - 1, lo), hi);
  int cand5 = min(max(c2,     lo), hi);
  float best = -3.0e38f;
  int cands[6] = {cand0, cand1, cand2, cand3, cand4, cand5};
  #pragma unroll
  for (int i = 0; i < 6; i++) {
    float s = (float)(cands[i] << 4);
    float v = fminf(bhi + s, ghi) - fmaxf(blo + s, glo) + 1.0f;
    best = fmaxf(best, v);
  }
  return best;
}

#define AG_LOAD(p)      __hip_atomic_load((p), __ATOMIC_RELAXED, __HIP_MEMORY_SCOPE_AGENT)
#define AG_STORE(p, v)  __hip_atomic_store((p), (v), __ATOMIC_RELAXED, __HIP_MEMORY_SCOPE_AGENT)

// ===========================================================================
// Merged worker kernel
// ===========================================================================
__global__ __launch_bounds__(256) void k_all(const float* __restrict__ gt,
                                             const int* __restrict__ imw_p,
                                             const int* __restrict__ imh_p,
                                             float* __restrict__ out_lab,
                                             float* __restrict__ out_adj,
                                             float* __restrict__ out_wts,
                                             uint32_t* __restrict__ ws,
                                             uint32_t kf0, uint32_t kf1,
                                             uint32_t kb0, uint32_t kb1) {
  #pragma clang fp contract(off)
  __shared__ float sg0[NG], sg1[NG], sg2[NG], sg3[NG], sga[NG], sgm[NG];
  __shared__ uint32_t sgmU[NG];
  __shared__ uint32_t sh[2 * NBIN];          // 16 KB; aliased as sc in fixup
  __shared__ unsigned long long sMask[4];
  __shared__ int sAnyZero, sLastB, sLastD;
  __shared__ uint32_t sSel[8];
  int tid = threadIdx.x;
  int b = blockIdx.x;
  int a = b >> 6, hb = (b & 63) << 2;        // anchor type, rows hb..hb+3
  {
    uint4* sh4 = (uint4*)sh;
    #pragma unroll
    for (int k = 0; k < 4; k++) sh4[tid + k * 256] = make_uint4(0, 0, 0, 0);
  }
  if (tid == 0) sAnyZero = 0;
  if (tid < NG) {
    const float4 g4 = ((const float4*)gt)[tid];
    sg0[tid] = g4.x; sg1[tid] = g4.y; sg2[tid] = g4.z; sg3[tid] = g4.w;
    float gw = g4.z - g4.x + 1.0f, gh = g4.w - g4.y + 1.0f;
    sga[tid] = (gw > 0.0f && gh > 0.0f) ? gw * gh : 0.0f;
    sgmU[tid] = 0u;
  }
  __syncthreads();   // S1

  // local analytic gmax (LDS atomicMax on float bits; IoU >= 0)
  {
    int imwi = imw_p[0], imhi = imh_p[0];
    for (int p = tid; p < NG * NUM_A; p += 256) {
      int g = p / NUM_A, q = p - g * NUM_A;
      float b0 = BA[q][0], b1 = BA[q][1], b2 = BA[q][2], b3 = BA[q][3];
      int ib0 = (int)b0, ib1 = (int)b1, ib2 = (int)b2, ib3 = (int)b3;
      int wlo = max(0, (-ib0 + 15) >> 4);
      int whi = min(255, (imwi - ib2 - 1) >> 4);
      int hlo = max(0, (-ib1 + 15) >> 4);
      int hhi = min(255, (imhi - ib3 - 1) >> 4);
      if (wlo > whi || hlo > hhi) continue;
      float iwb = axis_best(b0, b2, sg0[g], sg2[g], wlo, whi);
      float ihb = axis_best(b1, b3, sg1[g], sg3[g], hlo, hhi);
      float aw = b2 - b0 + 1.0f, ah = b3 - b1 + 1.0f;
      float aarea = aw * ah;
      float inter = (iwb > 0.0f && ihb > 0.0f) ? iwb * ihb : 0.0f;
      float den = aarea + sga[g] - inter;
      float o = inter / den;
      atomicMax(&sgmU[g], __float_as_uint(o));
    }
  }

  // per-wave y-mask
  {
    int wv = tid >> 6, g = tid & 63;
    float sy = (float)((hb + wv) << 4);
    float ihp = fminf(BA[a][3] + sy, sg3[g]) - fmaxf(BA[a][1] + sy, sg1[g]) + 1.0f;
    unsigned long long mk = __ballot(ihp > 0.0f);
    if (g == 0) sMask[wv] = mk;
  }
  __syncthreads();   // S2
  if (tid < NG) {
    uint32_t mm = sgmU[tid];
    sgm[tid] = __uint_as_float(mm);
    if (mm == 0u) atomicOr(&sAnyZero, 1);
  }
  __syncthreads();   // S3

  float BA0 = BA[a][0], BA1 = BA[a][1], BA2 = BA[a][2], BA3 = BA[a][3];
  float imw = (float)imw_p[0], imh = (float)imh_p[0];
  int w = tid;
  float sx = (float)(w << 4);
  float A0 = BA0 + sx, A2 = BA2 + sx;
  float aw = A2 - A0 + 1.0f;
  float A1v[4], A3v[4];
  #pragma unroll
  for (int r = 0; r < 4; r++) {
    float sy = (float)((hb + r) << 4);
    A1v[r] = BA1 + sy; A3v[r] = BA3 + sy;
  }
  float ah = A3v[0] - A1v[0] + 1.0f;
  float aarea = aw * ah;
  bool xv = (A0 >= 0.0f) && (A2 < imw);

  unsigned long long mk0 = sMask[0], mk1 = sMask[1],
                     mk2 = sMask[2], mk3 = sMask[3];
  unsigned long long uni = mk0 | mk1 | mk2 | mk3;
  float amaxv[4] = {0.f, 0.f, 0.f, 0.f};
  int bgv[4] = {0, 0, 0, 0};
  uint32_t afv = 0u;
  while (uni) {
    int g = __ffsll(uni) - 1;
    uni &= uni - 1;
    float iw = fminf(A2, sg2[g]) - fmaxf(A0, sg0[g]) + 1.0f;
    if (!__any(iw > 0.0f)) continue;
    if (iw > 0.0f) {
      float base = aarea + sga[g];
      float gy1 = sg1[g], gy2 = sg3[g], gm = sgm[g];
#define DO_ROW(r, mk)                                                     \
      if ((mk >> g) & 1ull) {                                             \
        float ih = fminf(A3v[r], gy2) - fmaxf(A1v[r], gy1) + 1.0f;        \
        float inter = iw * ih;                                            \
        float o = inter / (base - inter);                                 \
        if (o > amaxv[r]) { amaxv[r] = o; bgv[r] = g; }                   \
        if (o == gm) afv |= (1u << r);                                    \
      }
      DO_ROW(0, mk0) DO_ROW(1, mk1) DO_ROW(2, mk2) DO_ROW(3, mk3)
#undef DO_ROW
    }
  }

  bool anyZ = (sAnyZero != 0);
  uint32_t lm[4];
  #pragma unroll
  for (int r = 0; r < 4; r++) {
    int hw = (hb + r) * 256 + w;
    bool valid = xv && (A1v[r] >= 0.0f) && (A3v[r] < imh);
    float amax = amaxv[r];
    bool anyfg = (((afv >> r) & 1u) || anyZ) && valid;
    uint32_t lab;
    if (!valid)                       lab = LAB_IGN;
    else if (anyfg || amax >= 0.7f)   lab = LAB_FG;
    else if (amax < 0.3f)             lab = LAB_BG;
    else                              lab = LAB_IGN;

    float adj0 = 0.f, adj1 = 0.f, adj2 = 0.f, adj3 = 0.f;
    if (valid) {
      int bg = bgv[r];
      float G0 = sg0[bg], G1 = sg1[bg], G2 = sg2[bg], G3 = sg3[bg];
      float ax = (A2 + A0) * 0.5f, ay = (A3v[r] + A1v[r]) * 0.5f;
      float gwm = G2 - G0 + 1.0f, ghm = G3 - G1 + 1.0f;
      float gx = (G2 + G0) * 0.5f, gy = (G3 + G1) * 0.5f;
      adj0 = (gx - ax) / aw;
      adj1 = (gy - ay) / ah;
      adj2 = logf(gwm / aw);
      adj3 = logf(ghm / ah);
    }
    int c4 = a * 4;
    out_adj[(c4 + 0) * HW + hw] = adj0;
    out_adj[(c4 + 1) * HW + hw] = adj1;
    out_adj[(c4 + 2) * HW + hw] = adj2;
    out_adj[(c4 + 3) * HW + hw] = adj3;

    uint32_t m = 0u;
    uint32_t n = (uint32_t)(hw * 9 + a);
    if (lab != LAB_IGN) {
      uint32_t kk0 = (lab == LAB_FG) ? kf0 : kb0;
      uint32_t kk1 = (lab == LAB_FG) ? kf1 : kb1;
      m = mant_of(kk0, kk1, n);
      atomicAdd(&sh[((lab == LAB_FG) ? 0 : NBIN) + (m >> BIN_SHIFT)], 1u);
    }
    lm[r] = (lab << 24) | m;                 // stays in registers
  }

  __syncthreads();
  for (int i = tid; i < 2 * NBIN; i += 256) {
    uint32_t v = sh[i];
    if (v) atomicAdd(&ws[M_OFF_HF + i], v);  // device-scope -> at IF
  }
  asm volatile("s_waitcnt vmcnt(0)" ::: "memory");
  __syncthreads();

  // ---- barrier B: tree arrival; completer runs select ----
  if (tid == 0) {
    int last = 0;
    uint32_t v = atomicAdd(&ws[M_SUBB + (b & 31) * 16], 1u);
    if (v == 17u) {
      uint32_t r = atomicAdd(&ws[M_ROOTB], 1u);
      if (r == 31u) last = 1;
    }
    sLastB = last;
  }
  __syncthreads();
  if (sLastB) {
    for (int cls = 0; cls < 2; cls++) {
      uint32_t* hist = ws + (cls ? M_OFF_HB : M_OFF_HF);
      uint32_t* sel = ws + M_OFF_SEL + cls * 4;
      uint32_t loc[8], s = 0;
      #pragma unroll
      for (int j = 0; j < 8; j++) {
        loc[j] = AG_LOAD(&hist[tid * 8 + j]);
        s += loc[j];
      }
      sh[tid] = s; __syncthreads();
      for (int off = 1; off < 256; off <<= 1) {
        uint32_t v = (tid >= off) ? sh[tid - off] : 0u;
        __syncthreads();
        sh[tid] += v;
        __syncthreads();
      }
      uint32_t total = sh[255];
      uint32_t K = total < CAPK ? total : CAPK;
      if (tid == 0) {
        AG_STORE(&sel[3], K);
        if (K == 0u) {
          AG_STORE(&sel[0], 0xFFFFFFFFu); AG_STORE(&sel[1], 0u);
          AG_STORE(&sel[2], 0u);
        }
      }
      if (K > 0u) {
        uint32_t myC = sh[tid], pvC = (tid == 0) ? 0u : sh[tid - 1];
        if (myC >= K && pvC < K) {
          uint32_t cum = pvC; int bb = tid * 8;
          for (int j = 0; j < 8; j++) {
            if (cum + loc[j] >= K) { bb = tid * 8 + j; break; }
            cum += loc[j];
          }
          AG_STORE(&sel[0], (uint32_t)bb); AG_STORE(&sel[1], cum);
          AG_STORE(&sel[2], K - cum);
        }
      }
      __syncthreads();
    }
    asm volatile("s_waitcnt vmcnt(0)" ::: "memory");
    __syncthreads();
    if (tid == 0) AG_STORE(&ws[M_FLAGC], 1u);
  }

  // ---- spin on select-done flag (read-only loads, s_sleep backoff) ----
  if (tid == 0) {
    while (AG_LOAD(&ws[M_FLAGC]) == 0u) __builtin_amdgcn_s_sleep(4);
  }
  __syncthreads();
  if (tid < 8) sSel[tid] = AG_LOAD(&ws[M_OFF_SEL + tid]);
  __syncthreads();
  uint32_t bf = sSel[0], Kf = sSel[3], bbn = sSel[4], Kb = sSel[7];
  float inv = 1.0f / (float)(Kf + Kb);       // 1/num_ni

  // ---- emit from registers; boundary-bin -> candidates (disjoint writer) --
  #pragma unroll
  for (int r = 0; r < 4; r++) {
    int hw = (hb + r) * 256 + w;
    uint32_t lab = lm[r] >> 24;
    uint32_t m = lm[r] & 0x7FFFFFu;
    uint32_t n = (uint32_t)(hw * 9 + a);
    float outv = 2.0f, wv = 0.0f;
    bool skip = false;
    if (lab == LAB_FG) {
      uint32_t bn = m >> BIN_SHIFT;
      if (bn < bf) { outv = 1.0f; wv = inv; }
      else if (bn == bf) {
        uint32_t idx = atomicAdd(&ws[M_OFF_CNTF], 1u);
        if (idx < CAND_CAP) {
          AG_STORE((uint64_t*)(ws + M_CANDF) + idx,
                   ((uint64_t)m << 20) | (uint64_t)n);
          skip = true;
        }
      }
    } else if (lab == LAB_BG) {
      uint32_t bn = m >> BIN_SHIFT;
      if (bn < bbn) { outv = 0.0f; }
      else if (bn == bbn) {
        uint32_t idx = atomicAdd(&ws[M_OFF_CNTB], 1u);
        if (idx < CAND_CAP) {
          AG_STORE((uint64_t*)(ws + M_CANDB) + idx,
                   ((uint64_t)m << 20) | (uint64_t)n);
          skip = true;
        }
      }
    }
    if (!skip) {
      out_lab[a * HW + hw] = outv;
      int c4 = a * 4;
      out_wts[(c4 + 0) * HW + hw] = wv;
      out_wts[(c4 + 1) * HW + hw] = wv;
      out_wts[(c4 + 2) * HW + hw] = wv;
      out_wts[(c4 + 3) * HW + hw] = wv;
    }
  }

  asm volatile("s_waitcnt vmcnt(0)" ::: "memory");
  __syncthreads();

  // ---- barrier D: tree arrival; completer runs fixup; others exit ----
  if (tid == 0) {
    int last = 0;
    uint32_t v = atomicAdd(&ws[M_SUBD + (b & 31) * 16], 1u);
    if (v == 17u) {
      uint32_t r = atomicAdd(&ws[M_ROOTD], 1u);
      if (r == 31u) last = 1;
    }
    sLastD = last;
  }
  __syncthreads();
  if (sLastD) {
    uint64_t* sc = (uint64_t*)sh;            // 2048 x u64 = 16 KB alias
    for (int cls = 0; cls < 2; cls++) {
      uint32_t cnt = AG_LOAD(&ws[cls == 0 ? M_OFF_CNTF : M_OFF_CNTB]);
      uint32_t C = cnt < CAND_CAP ? cnt : CAND_CAP;
      uint32_t need = AG_LOAD(&ws[M_OFF_SEL + cls * 4 + 2]);
      const uint64_t* cand =
          (const uint64_t*)(ws + (cls == 0 ? M_CANDF : M_CANDB));
      for (uint32_t i = tid; i < C; i += 256) sc[i] = AG_LOAD(&cand[i]);
      __syncthreads();
      for (uint32_t i = tid; i < C; i += 256) {
        uint64_t k = sc[i];
        uint32_t rr = 0;
        for (uint32_t j = 0; j < C; j++) rr += (sc[j] < k) ? 1u : 0u;
        bool kept = (rr < need);
        uint32_t nn = (uint32_t)(k & 0xFFFFFu);
        uint32_t aa = nn % 9u, hww = nn / 9u;
        uint32_t tt = aa * HW + hww;
        float lv = kept ? (cls == 0 ? 1.0f : 0.0f) : 2.0f;
        float wvv = (kept && cls == 0) ? inv : 0.0f;
        AG_STORE(&out_lab[tt], lv);
        #pragma unroll
        for (int j2 = 0; j2 < 4; j2++)
          AG_STORE(&out_wts[(aa * 4 + j2) * HW + hww], wvv);
      }
      __syncthreads();
    }
  }
}

// ===========================================================================
// Fallback: proven Round-8 2-kernel pipeline (verbatim)
// ===========================================================================
__global__ __launch_bounds__(256) void k_main2(const float* __restrict__ gt,
                                               const int* __restrict__ imw_p,
                                               const int* __restrict__ imh_p,
                                               float* __restrict__ out_adj,
                                               uint32_t* __restrict__ ws,
                                               uint32_t kf0, uint32_t kf1,
                                               uint32_t kb0, uint32_t kb1) {
  #pragma clang fp contract(off)
  __shared__ float sg0[NG], sg1[NG], sg2[NG], sg3[NG], sga[NG], sgm[NG];
  __shared__ uint32_t sgmU[NG];
  __shared__ uint32_t sh[2 * NBIN];
  __shared__ unsigned long long sMask[4];
  __shared__ int sAnyZero, sLast;
  int tid = threadIdx.x;
  int b = blockIdx.x;
  int a = b >> 6, hb = (b & 63) << 2;
  {
    uint4* sh4 = (uint4*)sh;
    #pragma unroll
    for (int k = 0; k < 4; k++) sh4[tid + k * 256] = make_uint4(0, 0, 0, 0);
  }
  if (tid == 0) sAnyZero = 0;
  if (tid < NG) {
    const float4 g4 = ((const float4*)gt)[tid];
    sg0[tid] = g4.x; sg1[tid] = g4.y; sg2[tid] = g4.z; sg3[tid] = g4.w;
    float gw = g4.z - g4.x + 1.0f, gh = g4.w - g4.y + 1.0f;
    sga[tid] = (gw > 0.0f && gh > 0.0f) ? gw * gh : 0.0f;
    sgmU[tid] = 0u;
  }
  __syncthreads();

  {
    int imwi = imw_p[0], imhi = imh_p[0];
    for (int p = tid; p < NG * NUM_A; p += 256) {
      int g = p / NUM_A, q = p - g * NUM_A;
      float b0 = BA[q][0], b1 = BA[q][1], b2 = BA[q][2], b3 = BA[q][3];
      int ib0 = (int)b0, ib1 = (int)b1, ib2 = (int)b2, ib3 = (int)b3;
      int wlo = max(0, (-ib0 + 15) >> 4);
      int whi = min(255, (imwi - ib2 - 1) >> 4);
      int hlo = max(0, (-ib1 + 15) >> 4);
      int hhi = min(255, (imhi - ib3 - 1) >> 4);
      if (wlo > whi || hlo > hhi) continue;
      float iwb = axis_best(b0, b2, sg0[g], sg2[g], wlo, whi);
      float ihb = axis_best(b1, b3, sg1[g], sg3[g], hlo, hhi);
      float aw = b2 - b0 + 1.0f, ah = b3 - b1 + 1.0f;
      float aarea = aw * ah;
      float inter = (iwb > 0.0f && ihb > 0.0f) ? iwb * ihb : 0.0f;
      float den = aarea + sga[g] - inter;
      float o = inter / den;
      atomicMax(&sgmU[g], __float_as_uint(o));
    }
  }

  {
    int wv = tid >> 6, g = tid & 63;
    float sy = (float)((hb + wv) << 4);
    float ihp = fminf(BA[a][3] + sy, sg3[g]) - fmaxf(BA[a][1] + sy, sg1[g]) + 1.0f;
    unsigned long long mk = __ballot(ihp > 0.0f);
    if (g == 0) sMask[wv] = mk;
  }
  __syncthreads();
  if (tid < NG) {
    uint32_t mm = sgmU[tid];
    sgm[tid] = __uint_as_float(mm);
    if (mm == 0u) atomicOr(&sAnyZero, 1);
  }
  __syncthreads();

  float BA0 = BA[a][0], BA1 = BA[a][1], BA2 = BA[a][2], BA3 = BA[a][3];
  float imw = (float)imw_p[0], imh = (float)imh_p[0];
  int w = tid;
  float sx = (float)(w << 4);
  float A0 = BA0 + sx, A2 = BA2 + sx;
  float aw = A2 - A0 + 1.0f;
  float A1v[4], A3v[4];
  #pragma unroll
  for (int r = 0; r < 4; r++) {
    float sy = (float)((hb + r) << 4);
    A1v[r] = BA1 + sy; A3v[r] = BA3 + sy;
  }
  float ah = A3v[0] - A1v[0] + 1.0f;
  float aarea = aw * ah;
  bool xv = (A0 >= 0.0f) && (A2 < imw);

  unsigned long long mk0 = sMask[0], mk1 = sMask[1],
                     mk2 = sMask[2], mk3 = sMask[3];
  unsigned long long uni = mk0 | mk1 | mk2 | mk3;
  float amaxv[4] = {0.f, 0.f, 0.f, 0.f};
  int bgv[4] = {0, 0, 0, 0};
  uint32_t afv = 0u;
  while (uni) {
    int g = __ffsll(uni) - 1;
    uni &= uni - 1;
    float iw = fminf(A2, sg2[g]) - fmaxf(A0, sg0[g]) + 1.0f;
    if (!__any(iw > 0.0f)) continue;
    if (iw > 0.0f) {
      float base = aarea + sga[g];
      float gy1 = sg1[g], gy2 = sg3[g], gm = sgm[g];
#define DO_ROW(r, mk)                                                     \
      if ((mk >> g) & 1ull) {                                             \
        float ih = fminf(A3v[r], gy2) - fmaxf(A1v[r], gy1) + 1.0f;        \
        float inter = iw * ih;                                            \
        float o = inter / (base - inter);                                 \
        if (o > amaxv[r]) { amaxv[r] = o; bgv[r] = g; }                   \
        if (o == gm) afv |= (1u << r);                                    \
      }
      DO_ROW(0, mk0) DO_ROW(1, mk1) DO_ROW(2, mk2) DO_ROW(3, mk3)
#undef DO_ROW
    }
  }

  bool anyZ = (sAnyZero != 0);
  #pragma unroll
  for (int r = 0; r < 4; r++) {
    int hw = (hb + r) * 256 + w;
    bool valid = xv && (A1v[r] >= 0.0f) && (A3v[r] < imh);
    float amax = amaxv[r];
    bool anyfg = (((afv >> r) & 1u) || anyZ) && valid;
    uint32_t lab;
    if (!valid)                       lab = LAB_IGN;
    else if (anyfg || amax >= 0.7f)   lab = LAB_FG;
    else if (amax < 0.3f)             lab = LAB_BG;
    else                              lab = LAB_IGN;

    float adj0 = 0.f, adj1 = 0.f, adj2 = 0.f, adj3 = 0.f;
    if (valid) {
      int bg = bgv[r];
      float G0 = sg0[bg], G1 = sg1[bg], G2 = sg2[bg], G3 = sg3[bg];
      float ax = (A2 + A0) * 0.5f, ay = (A3v[r] + A1v[r]) * 0.5f;
      float gwm = G2 - G0 + 1.0f, ghm = G3 - G1 + 1.0f;
      float gx = (G2 + G0) * 0.5f, gy = (G3 + G1) * 0.5f;
      adj0 = (gx - ax) / aw;
      adj1 = (gy - ay) / ah;
      adj2 = logf(gwm / aw);
      adj3 = logf(ghm / ah);
    }
    int c4 = a * 4;
    out_adj[(c4 + 0) * HW + hw] = adj0;
    out_adj[(c4 + 1) * HW + hw] = adj1;
    out_adj[(c4 + 2) * HW + hw] = adj2;
    out_adj[(c4 + 3) * HW + hw] = adj3;

    uint32_t m = 0u;
    uint32_t n = (uint32_t)(hw * 9 + a);
    if (lab != LAB_IGN) {
      uint32_t kk0 = (lab == LAB_FG) ? kf0 : kb0;
      uint32_t kk1 = (lab == LAB_FG) ? kf1 : kb1;
      m = mant_of(kk0, kk1, n);
      atomicAdd(&sh[((lab == LAB_FG) ? 0 : NBIN) + (m >> BIN_SHIFT)], 1u);
    }
    ws[OFF_LABM + a * HW + hw] = (lab << 24) | m;
  }

  __syncthreads();
  for (int i = tid; i < 2 * NBIN; i += 256) {
    uint32_t v = sh[i];
    if (v) atomicAdd(&ws[OFF_HF + i], v);
  }
  __syncthreads();
  if (tid == 0) {
    int lastF = 0;
    uint32_t v = atomicAdd(&ws[OFF_SUB1 + (b & (SUB1_N - 1)) * 16], 1u);
    if (v == SUB1_Q - 1) {
      uint32_t r = atomicAdd(&ws[OFF_ROOT1], 1u);
      if (r == SUB1_N - 1) lastF = 1;
    }
    sLast = lastF;
  }
  __syncthreads();
  if (sLast) {
    for (int cls = 0; cls < 2; cls++) {
      uint32_t* hist = ws + (cls ? OFF_HB : OFF_HF);
      uint32_t* sel = ws + OFF_SEL + cls * 4;
      uint32_t loc[8], s = 0;
      #pragma unroll
      for (int j = 0; j < 8; j++) {
        loc[j] = AG_LOAD(&hist[tid * 8 + j]);
        s += loc[j];
      }
      sh[tid] = s; __syncthreads();
      for (int off = 1; off < 256; off <<= 1) {
        uint32_t v = (tid >= off) ? sh[tid - off] : 0u;
        __syncthreads();
        sh[tid] += v;
        __syncthreads();
      }
      uint32_t total = sh[255];
      uint32_t K = total < CAPK ? total : CAPK;
      if (tid == 0) {
        sel[3] = K;
        if (K == 0u) { sel[0] = 0xFFFFFFFFu; sel[1] = 0u; sel[2] = 0u; }
      }
      if (K > 0u) {
        uint32_t myC = sh[tid], pvC = (tid == 0) ? 0u : sh[tid - 1];
        if (myC >= K && pvC < K) {
          uint32_t cum = pvC; int bb = tid * 8;
          for (int j = 0; j < 8; j++) {
            if (cum + loc[j] >= K) { bb = tid * 8 + j; break; }
            cum += loc[j];
          }
          sel[0] = (uint32_t)bb; sel[1] = cum; sel[2] = K - cum;
        }
      }
      __syncthreads();
    }
  }
}

__global__ __launch_bounds__(256) void k_emitfix(float* __restrict__ out_lab,
                                                 float* __restrict__ out_wts,
                                                 uint32_t* __restrict__ ws) {
  __shared__ uint64_t sc[CAND_CAP];
  __shared__ int sLast;
  int tid = threadIdx.x;
  int t = blockIdx.x * 256 + tid;
  uint32_t lm = ws[OFF_LABM + t];
  uint32_t lab = lm >> 24;
  uint32_t m = lm & 0x7FFFFFu;
  uint32_t bf = ws[OFF_SEL + 0], bb = ws[OFF_SEL + 4];
  uint32_t Kf = ws[OFF_SEL + 3], Kb = ws[OFF_SEL + 7];
  float inv = 1.0f / (float)(Kf + Kb);
  int a = t >> 16, hw = t & 65535;
  uint32_t n = (uint32_t)(hw * 9 + a);

  float outv = 2.0f, wv = 0.0f;
  bool skip = false;
  if (lab == LAB_FG) {
    uint32_t bn = m >> BIN_SHIFT;
    if (bn < bf) { outv = 1.0f; wv = inv; }
    else if (bn == bf) {
      uint32_t idx = atomicAdd(&ws[OFF_CNTF], 1u);
      if (idx < CAND_CAP) {
        AG_STORE((uint64_t*)(ws + OFF_CANDF) + idx,
                 ((uint64_t)m << 20) | (uint64_t)n);
        skip = true;
      }
    }
  } else if (lab == LAB_BG) {
    uint32_t bn = m >> BIN_SHIFT;
    if (bn < bb) { outv = 0.0f; }
    else if (bn == bb) {
      uint32_t idx = atomicAdd(&ws[OFF_CNTB], 1u);
      if (idx < CAND_CAP) {
        AG_STORE((uint64_t*)(ws + OFF_CANDB) + idx,
                 ((uint64_t)m << 20) | (uint64_t)n);
        skip = true;
      }
    }
  }
  if (!skip) {
    out_lab[t] = outv;
    int c4 = a * 4;
    out_wts[(c4 + 0) * HW + hw] = wv;
    out_wts[(c4 + 1) * HW + hw] = wv;
    out_wts[(c4 + 2) * HW + hw] = wv;
    out_wts[(c4 + 3) * HW + hw] = wv;
  }

  asm volatile("s_waitcnt vmcnt(0)" ::: "memory");
  __syncthreads();
  if (tid == 0) {
    int lastF = 0;
    uint32_t v = atomicAdd(&ws[OFF_SUB2 + (blockIdx.x & (SUB2_N - 1)) * 16], 1u);
    if (v == SUB2_Q - 1) {
      uint32_t r = atomicAdd(&ws[OFF_ROOT2], 1u);
      if (r == SUB2_N - 1) lastF = 1;
    }
    sLast = lastF;
  }
  __syncthreads();
  if (sLast) {
    for (int cls = 0; cls < 2; cls++) {
      uint32_t cnt = AG_LOAD(&ws[cls == 0 ? OFF_CNTF : OFF_CNTB]);
      uint32_t C = cnt < CAND_CAP ? cnt : CAND_CAP;
      uint32_t need = AG_LOAD(&ws[OFF_SEL + cls * 4 + 2]);
      const uint64_t* cand =
          (const uint64_t*)(ws + (cls == 0 ? OFF_CANDF : OFF_CANDB));
      for (uint32_t i = tid; i < C; i += 256) sc[i] = AG_LOAD(&cand[i]);
      __syncthreads();
      for (uint32_t i = tid; i < C; i += 256) {
        uint64_t k = sc[i];
        uint32_t rr = 0;
        for (uint32_t j = 0; j < C; j++) rr += (sc[j] < k) ? 1u : 0u;
        bool kept = (rr < need);
        uint32_t nn = (uint32_t)(k & 0xFFFFFu);
        uint32_t aa = nn % 9u, hww = nn / 9u;
        uint32_t tt = aa * HW + hww;
        float lv = kept ? (cls == 0 ? 1.0f : 0.0f) : 2.0f;
        float wvv = (kept && cls == 0) ? inv : 0.0f;
        AG_STORE(&out_lab[tt], lv);
        #pragma unroll
        for (int j2 = 0; j2 < 4; j2++)
          AG_STORE(&out_wts[(aa * 4 + j2) * HW + hww], wvv);
      }
      __syncthreads();
    }
  }
}

extern "C" void kernel_launch(void* const* d_in, const int* in_sizes, int n_in,
                              void* d_out, int out_size, void* d_ws,
                              size_t ws_size, hipStream_t stream) {
  const float* gt  = (const float*)d_in[1];
  const int*   imw = (const int*)d_in[2];
  const int*   imh = (const int*)d_in[3];
  float* out      = (float*)d_out;
  float* out_lab  = out;                   // 589824
  float* out_adj  = out + N_ANCH;          // 4*589824
  float* out_wts  = out + 5 * N_ANCH;      // 4*589824
  uint32_t* ws = (uint32_t*)d_ws;

  uint32_t kf0, kf1, kb0, kb1;
  tf2x32(0u, 42u, 0u, 0u, &kf0, &kf1);
  tf2x32(0u, 42u, 0u, 1u, &kb0, &kb1);

  hipMemsetAsync(ws, 0, M_CTRL * sizeof(uint32_t), stream);
  void* kargs[] = {(void*)&gt,      (void*)&imw,     (void*)&imh,
                   (void*)&out_lab, (void*)&out_adj, (void*)&out_wts,
                   (void*)&ws,      (void*)&kf0,     (void*)&kf1,
                   (void*)&kb0,     (void*)&kb1};
  hipError_t err = hipLaunchCooperativeKernel(
      (const void*)k_all, dim3(NBLK_MAIN), dim3(256), kargs, 0, stream);
  if (err != hipSuccess) {
    (void)hipGetLastError();  // clear sticky error; proven 2-kernel fallback
    hipMemsetAsync(ws, 0, CTRL_WORDS * sizeof(uint32_t), stream);
    hipLaunchKernelGGL(k_main2, dim3(NBLK_MAIN), dim3(256), 0, stream, gt,
                       imw, imh, out_adj, ws, kf0, kf1, kb0, kb1);
    hipLaunchKernelGGL(k_emitfix, dim3(NBLK_EMIT), dim3(256), 0, stream,
                       out_lab, out_wts, ws);
  }
}

// Round 8
// 98.768 us; speedup vs baseline: 1.3113x; 1.3113x over previous
//
#include <hip/hip_runtime.h>
#include <stdint.h>

// ===========================================================================
// AnchorDataGenerator (Faster R-CNN anchor target layer), MI355X / gfx950
// Round 11: memset + ONE worker kernel (regular launch).
// Hazard fix vs Round 10: the in-kernel ZFLAG zero-gate relied on harness
// re-poison to clear stale MAGIC flags between runs -> deadlock if two runs
// occur without an intervening poison (rigor.md "re-poison semantics").
// Reinstated hipMemsetAsync (stream-ordered, per-run-clean ctrl region incl.
// CFLAG) and dropped the ZFLAG gate entirely.
// Kept (all individually validated):
//   - merged compute+emit, (lab,mant) in registers, LABM eliminated (R6/R9)
//   - tree arrival counters, 64B-strided (R8: flat chain = 28ns/RMW = 64us)
//   - fanned-out CFLAG spin, 32 sub-flags x 64B, <=18 pollers each
//     (R6/R9: single-address load spin saturates one IF sector -> 44us)
//   - regular launch, NOT cooperative (R9: coop adds ~10-20us/dispatch;
//     co-residency by capacity: 576 x 18.4KB LDS -> 2048 slots >> 576)
//   - agent-scope relaxed atomics only; vmcnt(0) drain before arrivals;
//     disjoint-writer boundary candidates; completer-block select & fixup.
// ===========================================================================

#define NUM_A 9
#define HW 65536
#define N_ANCH 589824
#define NG 64
#define CAPK 128u
#define NBIN 2048
#define BIN_SHIFT 12
#define CAND_CAP 2048

#define LAB_BG 0u
#define LAB_FG 1u
#define LAB_IGN 2u

#define NBLK 576

// workspace layout (u32 units)
#define OFF_HF    0                      // 2048 fg hist
#define OFF_HB    NBIN                   // 2048 bg hist
#define OFF_CNTF  (2*NBIN)               // 4096
#define OFF_CNTB  (OFF_CNTF + 1)         // 4097
#define OFF_ROOTB (OFF_CNTF + 2)         // 4098
#define OFF_ROOTD (OFF_CNTF + 3)         // 4099
#define OFF_SEL   4104                   // ..4111 {bin,below,need,K} x2
#define OFF_SUBB  4112                   // 32 x stride16
#define OFF_SUBD  (OFF_SUBB + 32*16)     // 4624
#define OFF_CFLG  (OFF_SUBD + 32*16)     // 5136: 32 x stride16
#define CTRL_WORDS (OFF_CFLG + 32*16)    // 5648 words = 22.6 KB memset
#define OFF_CANDF CTRL_WORDS             // 5648 (byte 22592, 8B aligned)
#define OFF_CANDB (OFF_CANDF + 2*CAND_CAP) // 9744; end 13840 (~55KB)

#define MAGIC_C 0x5CA1AB1Eu

__constant__ float BA[NUM_A][4] = {
  { -84.f,  -40.f,  99.f,  55.f}, {-176.f,  -88.f, 191.f, 103.f},
  {-360.f, -184.f, 375.f, 199.f}, { -56.f,  -56.f,  71.f,  71.f},
  {-120.f, -120.f, 135.f, 135.f}, {-248.f, -248.f, 263.f, 263.f},
  { -36.f,  -80.f,  51.f,  95.f}, { -80.f, -168.f,  95.f, 183.f},
  {-168.f, -344.f, 183.f, 359.f}};

__host__ __device__ static inline void tf2x32(uint32_t k0, uint32_t k1,
                                              uint32_t x0, uint32_t x1,
                                              uint32_t* o0, uint32_t* o1) {
  const uint32_t ks2 = k0 ^ k1 ^ 0x1BD11BDAu;
#define TF_R(r) { x0 += x1; x1 = (x1 << (r)) | (x1 >> (32 - (r))); x1 ^= x0; }
  x0 += k0; x1 += k1;
  TF_R(13) TF_R(15) TF_R(26) TF_R(6)
  x0 += k1;  x1 += ks2 + 1u;
  TF_R(17) TF_R(29) TF_R(16) TF_R(24)
  x0 += ks2; x1 += k0 + 2u;
  TF_R(13) TF_R(15) TF_R(26) TF_R(6)
  x0 += k0;  x1 += k1 + 3u;
  TF_R(17) TF_R(29) TF_R(16) TF_R(24)
  x0 += k1;  x1 += ks2 + 4u;
  TF_R(13) TF_R(15) TF_R(26) TF_R(6)
  x0 += ks2; x1 += k0 + 5u;
#undef TF_R
  *o0 = x0; *o1 = x1;
}

__device__ static inline uint32_t mant_of(uint32_t k0, uint32_t k1, uint32_t n) {
  uint32_t o0, o1;
  tf2x32(k0, k1, 0u, n, &o0, &o1);
  return (o0 ^ o1) >> 9;
}

// Max of fl(iw) over valid integer shifts [lo,hi] for one axis (concave,
// unimodal; max at clamped floor/ceil of continuous argmax endpoints).
__device__ static inline float axis_best(float blo, float bhi, float glo,
                                         float ghi, int lo, int hi) {
  #pragma clang fp contract(off)
  float t1 = (ghi - bhi) * 0.0625f;
  float t2 = (glo - blo) * 0.0625f;
  float tmin = fminf(t1, t2), tmax = fmaxf(t1, t2);
  int c1 = (int)floorf(tmin), c2 = (int)ceilf(tmax);
  int cand0 = lo, cand1 = hi;
  int cand2 = min(max(c1,     lo), hi);
  int cand3 = min(max(c1 + 1, lo), hi);
  int cand4 = min(max(c2 - 1, lo), hi);
  int cand5 = min(max(c2,     lo), hi);
  float best = -3.0e38f;
  int cands[6] = {cand0, cand1, cand2, cand3, cand4, cand5};
  #pragma unroll
  for (int i = 0; i < 6; i++) {
    float s = (float)(cands[i] << 4);
    float v = fminf(bhi + s, ghi) - fmaxf(blo + s, glo) + 1.0f;
    best = fmaxf(best, v);
  }
  return best;
}

#define AG_LOAD(p)      __hip_atomic_load((p), __ATOMIC_RELAXED, __HIP_MEMORY_SCOPE_AGENT)
#define AG_STORE(p, v)  __hip_atomic_store((p), (v), __ATOMIC_RELAXED, __HIP_MEMORY_SCOPE_AGENT)

__global__ __launch_bounds__(256) void k_one(const float* __restrict__ gt,
                                             const int* __restrict__ imw_p,
                                             const int* __restrict__ imh_p,
                                             float* __restrict__ out_lab,
                                             float* __restrict__ out_adj,
                                             float* __restrict__ out_wts,
                                             uint32_t* __restrict__ ws,
                                             uint32_t kf0, uint32_t kf1,
                                             uint32_t kb0, uint32_t kb1) {
  #pragma clang fp contract(off)
  __shared__ float sg0[NG], sg1[NG], sg2[NG], sg3[NG], sga[NG], sgm[NG];
  __shared__ uint32_t sgmU[NG];
  __shared__ uint32_t sh[2 * NBIN];          // 16 KB; aliased as sc in fixup
  __shared__ unsigned long long sMask[4];
  __shared__ int sAnyZero, sLastB, sLastD;
  __shared__ uint32_t sSel[8];
  int tid = threadIdx.x;
  int b = blockIdx.x;
  int a = b >> 6, hb = (b & 63) << 2;        // anchor type, rows hb..hb+3

  {
    uint4* sh4 = (uint4*)sh;
    #pragma unroll
    for (int k = 0; k < 4; k++) sh4[tid + k * 256] = make_uint4(0, 0, 0, 0);
  }
  if (tid == 0) sAnyZero = 0;
  if (tid < NG) {
    const float4 g4 = ((const float4*)gt)[tid];
    sg0[tid] = g4.x; sg1[tid] = g4.y; sg2[tid] = g4.z; sg3[tid] = g4.w;
    float gw = g4.z - g4.x + 1.0f, gh = g4.w - g4.y + 1.0f;
    sga[tid] = (gw > 0.0f && gh > 0.0f) ? gw * gh : 0.0f;
    sgmU[tid] = 0u;
  }
  __syncthreads();   // S1

  // ---- local analytic gmax (LDS atomicMax on float bits; IoU >= 0) ----
  {
    int imwi = imw_p[0], imhi = imh_p[0];
    for (int p = tid; p < NG * NUM_A; p += 256) {
      int g = p / NUM_A, q = p - g * NUM_A;
      float b0 = BA[q][0], b1 = BA[q][1], b2 = BA[q][2], b3 = BA[q][3];
      int ib0 = (int)b0, ib1 = (int)b1, ib2 = (int)b2, ib3 = (int)b3;
      int wlo = max(0, (-ib0 + 15) >> 4);
      int whi = min(255, (imwi - ib2 - 1) >> 4);
      int hlo = max(0, (-ib1 + 15) >> 4);
      int hhi = min(255, (imhi - ib3 - 1) >> 4);
      if (wlo > whi || hlo > hhi) continue;
      float iwb = axis_best(b0, b2, sg0[g], sg2[g], wlo, whi);
      float ihb = axis_best(b1, b3, sg1[g], sg3[g], hlo, hhi);
      float aw = b2 - b0 + 1.0f, ah = b3 - b1 + 1.0f;
      float aarea = aw * ah;
      float inter = (iwb > 0.0f && ihb > 0.0f) ? iwb * ihb : 0.0f;
      float den = aarea + sga[g] - inter;
      float o = inter / den;
      atomicMax(&sgmU[g], __float_as_uint(o));
    }
  }

  // per-wave y-mask
  {
    int wv = tid >> 6, g = tid & 63;
    float sy = (float)((hb + wv) << 4);
    float ihp = fminf(BA[a][3] + sy, sg3[g]) - fmaxf(BA[a][1] + sy, sg1[g]) + 1.0f;
    unsigned long long mk = __ballot(ihp > 0.0f);
    if (g == 0) sMask[wv] = mk;
  }
  __syncthreads();   // S2
  if (tid < NG) {
    uint32_t mm = sgmU[tid];
    sgm[tid] = __uint_as_float(mm);
    if (mm == 0u) atomicOr(&sAnyZero, 1);
  }
  __syncthreads();   // S3

  float BA0 = BA[a][0], BA1 = BA[a][1], BA2 = BA[a][2], BA3 = BA[a][3];
  float imw = (float)imw_p[0], imh = (float)imh_p[0];
  int w = tid;
  float sx = (float)(w << 4);
  float A0 = BA0 + sx, A2 = BA2 + sx;
  float aw = A2 - A0 + 1.0f;
  float A1v[4], A3v[4];
  #pragma unroll
  for (int r = 0; r < 4; r++) {
    float sy = (float)((hb + r) << 4);
    A1v[r] = BA1 + sy; A3v[r] = BA3 + sy;
  }
  float ah = A3v[0] - A1v[0] + 1.0f;
  float aarea = aw * ah;
  bool xv = (A0 >= 0.0f) && (A2 < imw);

  unsigned long long mk0 = sMask[0], mk1 = sMask[1],
                     mk2 = sMask[2], mk3 = sMask[3];
  unsigned long long uni = mk0 | mk1 | mk2 | mk3;
  float amaxv[4] = {0.f, 0.f, 0.f, 0.f};
  int bgv[4] = {0, 0, 0, 0};
  uint32_t afv = 0u;
  while (uni) {
    int g = __ffsll(uni) - 1;
    uni &= uni - 1;
    float iw = fminf(A2, sg2[g]) - fmaxf(A0, sg0[g]) + 1.0f;
    if (!__any(iw > 0.0f)) continue;
    if (iw > 0.0f) {
      float base = aarea + sga[g];
      float gy1 = sg1[g], gy2 = sg3[g], gm = sgm[g];
#define DO_ROW(r, mk)                                                     \
      if ((mk >> g) & 1ull) {                                             \
        float ih = fminf(A3v[r], gy2) - fmaxf(A1v[r], gy1) + 1.0f;        \
        float inter = iw * ih;                                            \
        float o = inter / (base - inter);                                 \
        if (o > amaxv[r]) { amaxv[r] = o; bgv[r] = g; }                   \
        if (o == gm) afv |= (1u << r);                                    \
      }
      DO_ROW(0, mk0) DO_ROW(1, mk1) DO_ROW(2, mk2) DO_ROW(3, mk3)
#undef DO_ROW
    }
  }

  bool anyZ = (sAnyZero != 0);
  uint32_t lm[4];
  #pragma unroll
  for (int r = 0; r < 4; r++) {
    int hw = (hb + r) * 256 + w;
    bool valid = xv && (A1v[r] >= 0.0f) && (A3v[r] < imh);
    float amax = amaxv[r];
    bool anyfg = (((afv >> r) & 1u) || anyZ) && valid;
    uint32_t lab;
    if (!valid)                       lab = LAB_IGN;
    else if (anyfg || amax >= 0.7f)   lab = LAB_FG;
    else if (amax < 0.3f)             lab = LAB_BG;
    else                              lab = LAB_IGN;

    float adj0 = 0.f, adj1 = 0.f, adj2 = 0.f, adj3 = 0.f;
    if (valid) {
      int bg = bgv[r];
      float G0 = sg0[bg], G1 = sg1[bg], G2 = sg2[bg], G3 = sg3[bg];
      float ax = (A2 + A0) * 0.5f, ay = (A3v[r] + A1v[r]) * 0.5f;
      float gwm = G2 - G0 + 1.0f, ghm = G3 - G1 + 1.0f;
      float gx = (G2 + G0) * 0.5f, gy = (G3 + G1) * 0.5f;
      adj0 = (gx - ax) / aw;
      adj1 = (gy - ay) / ah;
      adj2 = logf(gwm / aw);
      adj3 = logf(ghm / ah);
    }
    int c4 = a * 4;
    out_adj[(c4 + 0) * HW + hw] = adj0;
    out_adj[(c4 + 1) * HW + hw] = adj1;
    out_adj[(c4 + 2) * HW + hw] = adj2;
    out_adj[(c4 + 3) * HW + hw] = adj3;

    uint32_t m = 0u;
    uint32_t n = (uint32_t)(hw * 9 + a);
    if (lab != LAB_IGN) {
      uint32_t kk0 = (lab == LAB_FG) ? kf0 : kb0;
      uint32_t kk1 = (lab == LAB_FG) ? kf1 : kb1;
      m = mant_of(kk0, kk1, n);
      atomicAdd(&sh[((lab == LAB_FG) ? 0 : NBIN) + (m >> BIN_SHIFT)], 1u);
    }
    lm[r] = (lab << 24) | m;                 // stays in registers
  }
  __syncthreads();

  // ---- global hist add (ctrl region pre-zeroed by stream-ordered memset) --
  for (int i = tid; i < 2 * NBIN; i += 256) {
    uint32_t v = sh[i];
    if (v) atomicAdd(&ws[OFF_HF + i], v);
  }
  asm volatile("s_waitcnt vmcnt(0)" ::: "memory");
  __syncthreads();

  // ---- barrier B: tree arrival; completer runs select ----
  if (tid == 0) {
    int last = 0;
    uint32_t v = atomicAdd(&ws[OFF_SUBB + (b & 31) * 16], 1u);
    if (v == 17u) {
      uint32_t r = atomicAdd(&ws[OFF_ROOTB], 1u);
      if (r == 31u) last = 1;
    }
    sLastB = last;
  }
  __syncthreads();
  if (sLastB) {
    for (int cls = 0; cls < 2; cls++) {
      uint32_t* hist = ws + (cls ? OFF_HB : OFF_HF);
      uint32_t* sel = ws + OFF_SEL + cls * 4;
      uint32_t loc[8], s = 0;
      #pragma unroll
      for (int j = 0; j < 8; j++) {
        loc[j] = AG_LOAD(&hist[tid * 8 + j]);
        s += loc[j];
      }
      sh[tid] = s; __syncthreads();
      for (int off = 1; off < 256; off <<= 1) {
        uint32_t v = (tid >= off) ? sh[tid - off] : 0u;
        __syncthreads();
        sh[tid] += v;
        __syncthreads();
      }
      uint32_t total = sh[255];
      uint32_t K = total < CAPK ? total : CAPK;
      if (tid == 0) {
        AG_STORE(&sel[3], K);
        if (K == 0u) {
          AG_STORE(&sel[0], 0xFFFFFFFFu); AG_STORE(&sel[1], 0u);
          AG_STORE(&sel[2], 0u);
        }
      }
      if (K > 0u) {
        uint32_t myC = sh[tid], pvC = (tid == 0) ? 0u : sh[tid - 1];
        if (myC >= K && pvC < K) {
          uint32_t cum = pvC; int bb = tid * 8;
          for (int j = 0; j < 8; j++) {
            if (cum + loc[j] >= K) { bb = tid * 8 + j; break; }
            cum += loc[j];
          }
          AG_STORE(&sel[0], (uint32_t)bb); AG_STORE(&sel[1], cum);
          AG_STORE(&sel[2], K - cum);
        }
      }
      __syncthreads();
    }
    asm volatile("s_waitcnt vmcnt(0)" ::: "memory");
    __syncthreads();                         // all SEL stores at IF
    if (tid < 32) AG_STORE(&ws[OFF_CFLG + tid * 16], MAGIC_C);
  }

  // ---- fanned-out wake: poll OWN sub-flag (<=18 pollers/address) ----
  if (tid == 0) {
    while (AG_LOAD(&ws[OFF_CFLG + (b & 31) * 16]) != MAGIC_C)
      __builtin_amdgcn_s_sleep(2);
  }
  __syncthreads();
  if (tid < 8) sSel[tid] = AG_LOAD(&ws[OFF_SEL + tid]);
  __syncthreads();
  uint32_t bf = sSel[0], Kf = sSel[3], bbn = sSel[4], Kb = sSel[7];
  float inv = 1.0f / (float)(Kf + Kb);       // 1/num_ni

  // ---- emit from registers; boundary-bin -> candidates (disjoint writer) --
  #pragma unroll
  for (int r = 0; r < 4; r++) {
    int hw = (hb + r) * 256 + w;
    uint32_t lab = lm[r] >> 24;
    uint32_t m = lm[r] & 0x7FFFFFu;
    uint32_t n = (uint32_t)(hw * 9 + a);
    float outv = 2.0f, wv = 0.0f;
    bool skip = false;
    if (lab == LAB_FG) {
      uint32_t bn = m >> BIN_SHIFT;
      if (bn < bf) { outv = 1.0f; wv = inv; }
      else if (bn == bf) {
        uint32_t idx = atomicAdd(&ws[OFF_CNTF], 1u);
        if (idx < CAND_CAP) {
          AG_STORE((uint64_t*)(ws + OFF_CANDF) + idx,
                   ((uint64_t)m << 20) | (uint64_t)n);
          skip = true;
        }
      }
    } else if (lab == LAB_BG) {
      uint32_t bn = m >> BIN_SHIFT;
      if (bn < bbn) { outv = 0.0f; }
      else if (bn == bbn) {
        uint32_t idx = atomicAdd(&ws[OFF_CNTB], 1u);
        if (idx < CAND_CAP) {
          AG_STORE((uint64_t*)(ws + OFF_CANDB) + idx,
                   ((uint64_t)m << 20) | (uint64_t)n);
          skip = true;
        }
      }
    }
    if (!skip) {
      out_lab[a * HW + hw] = outv;
      int c4 = a * 4;
      out_wts[(c4 + 0) * HW + hw] = wv;
      out_wts[(c4 + 1) * HW + hw] = wv;
      out_wts[(c4 + 2) * HW + hw] = wv;
      out_wts[(c4 + 3) * HW + hw] = wv;
    }
  }

  asm volatile("s_waitcnt vmcnt(0)" ::: "memory");
  __syncthreads();

  // ---- barrier D: tree arrival; completer runs fixup; others exit ----
  if (tid == 0) {
    int last = 0;
    uint32_t v = atomicAdd(&ws[OFF_SUBD + (b & 31) * 16], 1u);
    if (v == 17u) {
      uint32_t r = atomicAdd(&ws[OFF_ROOTD], 1u);
      if (r == 31u) last = 1;
    }
    sLastD = last;
  }
  __syncthreads();
  if (sLastD) {
    uint64_t* sc = (uint64_t*)sh;            // 2048 x u64 = 16 KB alias
    for (int cls = 0; cls < 2; cls++) {
      uint32_t cnt = AG_LOAD(&ws[cls == 0 ? OFF_CNTF : OFF_CNTB]);
      uint32_t C = cnt < CAND_CAP ? cnt : CAND_CAP;
      uint32_t need = AG_LOAD(&ws[OFF_SEL + cls * 4 + 2]);
      const uint64_t* cand =
          (const uint64_t*)(ws + (cls == 0 ? OFF_CANDF : OFF_CANDB));
      for (uint32_t i = tid; i < C; i += 256) sc[i] = AG_LOAD(&cand[i]);
      __syncthreads();
      for (uint32_t i = tid; i < C; i += 256) {
        uint64_t k = sc[i];
        uint32_t rr = 0;
        for (uint32_t j = 0; j < C; j++) rr += (sc[j] < k) ? 1u : 0u;
        bool kept = (rr < need);
        uint32_t nn = (uint32_t)(k & 0xFFFFFu);
        uint32_t aa = nn % 9u, hww = nn / 9u;
        uint32_t tt = aa * HW + hww;
        float lv = kept ? (cls == 0 ? 1.0f : 0.0f) : 2.0f;
        float wvv = (kept && cls == 0) ? inv : 0.0f;
        AG_STORE(&out_lab[tt], lv);
        #pragma unroll
        for (int j2 = 0; j2 < 4; j2++)
          AG_STORE(&out_wts[(aa * 4 + j2) * HW + hww], wvv);
      }
      __syncthreads();
    }
  }
}

extern "C" void kernel_launch(void* const* d_in, const int* in_sizes, int n_in,
                              void* d_out, int out_size, void* d_ws,
                              size_t ws_size, hipStream_t stream) {
  const float* gt  = (const float*)d_in[1];
  const int*   imw = (const int*)d_in[2];
  const int*   imh = (const int*)d_in[3];
  float* out      = (float*)d_out;
  float* out_lab  = out;                   // 589824
  float* out_adj  = out + N_ANCH;          // 4*589824
  float* out_wts  = out + 5 * N_ANCH;      // 4*589824
  uint32_t* ws = (uint32_t*)d_ws;          // ~55 KB used

  uint32_t kf0, kf1, kb0, kb1;
  tf2x32(0u, 42u, 0u, 0u, &kf0, &kf1);
  tf2x32(0u, 42u, 0u, 1u, &kb0, &kb1);

  // Stream-ordered zero of ctrl region (incl. CFLAG sub-flags): every run
  // starts clean regardless of harness poison timing.
  hipMemsetAsync(ws, 0, CTRL_WORDS * sizeof(uint32_t), stream);
  // Residency by capacity: 576 blocks, 18.4KB LDS -> 8 blocks/CU (2048
  // slots) >> 576, 28 VGPR; sole kernel on the stream -> all co-resident.
  hipLaunchKernelGGL(k_one, dim3(NBLK), dim3(256), 0, stream, gt, imw, imh,
                     out_lab, out_adj, out_wts, ws, kf0, kf1, kb0, kb1);
}